// Round 13
// baseline (456.737 us; speedup 1.0000x reference)
//
#include <hip/hip_runtime.h>
#include <stdint.h>

#define MM 16384
#define KK 2048
#define NN 2048
#define GG 64
#define EPSV 1e-5f
#define NT 32           // K tiles of 64

typedef short short8 __attribute__((ext_vector_type(8)));
typedef float floatx16 __attribute__((ext_vector_type(16)));

__device__ __forceinline__ uint16_t f2bf(float f) {
  uint32_t u = __float_as_uint(f);
  u = (u + 0x7fffu + ((u >> 16) & 1u)) >> 16;
  return (uint16_t)u;
}

__global__ void cvt_f32_to_bf16(const float* __restrict__ src,
                                uint16_t* __restrict__ dst, int n4) {
  int stride = gridDim.x * blockDim.x;
  for (int i = blockIdx.x * blockDim.x + threadIdx.x; i < n4; i += stride) {
    float4 v = reinterpret_cast<const float4*>(src)[i];
    ushort4 o;
    o.x = f2bf(v.x); o.y = f2bf(v.y); o.z = f2bf(v.z); o.w = f2bf(v.w);
    reinterpret_cast<ushort4*>(dst)[i] = o;
  }
}

__device__ __forceinline__ void gload_lds16(const void* g, void* l) {
  __builtin_amdgcn_global_load_lds(
      (const __attribute__((address_space(1))) void*)g,
      (__attribute__((address_space(3))) void*)l, 16, 0, 0);
}

// DPP 16-lane row reduction + xor16 merge -> sum over each 32-lane half.
#define ROR_ADD(v, n)                                                      \
  v += __int_as_float(__builtin_amdgcn_update_dpp(                         \
      0, __float_as_int(v), 0x120 + (n), 0xF, 0xF, true))
#define RED32(v)                                                           \
  { ROR_ADD(v, 1); ROR_ADD(v, 2); ROR_ADD(v, 4); ROR_ADD(v, 8);            \
    v += __shfl_xor(v, 16, 64); }

// r13 = r7 base (best GEMM structure, 174.5us) with 32x32x16 MFMA fragments.
// Rationale: 12 schedule variants all pinned at MfmaUtil 33-35% -> pipes are
// demand-serialized. 32x32x16 changes the DEMAND: matrix-pipe 2483->2066
// cyc/K-tile (m119: 8.07cyc/32k-FLOP vs 4.85/16k), MFMA instr count 64->32
// per wave per tile, identical LDS bytes and ds_read count (24x b128).
// Swizzle verified conflict-free for the 32x32 pattern (uniform 8 lanes per
// 16B slot = b128 minimum). C/D layout per m74/m101: col=lane&31,
// row=(reg&3)+8*(reg>>2)+4*(lane>>5); A/B operand k=(lane>>5)*8+j (mirror of
// the verified 16x16 mapping). Each 32-col B-frag = exactly one GN group.
// r12's B-direct reverted (2x FETCH + vmcnt serialization).
__global__ __launch_bounds__(512, 2)
void gemm_gn_silu_32(const uint16_t* __restrict__ xb,  // M x K bf16
                     const uint16_t* __restrict__ wb,  // N x K bf16
                     const float* __restrict__ bias,   // N
                     const float* __restrict__ gnw,    // G
                     const float* __restrict__ gnb,    // G
                     const float* __restrict__ mw,     // N
                     float* __restrict__ out) {        // M x N f32
  extern __shared__ char lds[];   // 131072 bytes

  int bid = blockIdx.x;
  // XCD chunk swizzle: 512 blocks, 8 XCDs, 64 consecutive tiles per XCD.
  int wgs = ((bid & 7) << 6) | (bid >> 3);
  int tm = wgs >> 3;          // 0..63  (M tiles of 256)
  int tn = wgs & 7;           // 0..7   (N tiles of 256)
  int row0 = tm * 256;
  int col0 = tn * 256;

  int t = threadIdx.x;
  int lane = t & 63;
  int wid = t >> 6;
  int wm = wid >> 2, wn = wid & 3;   // 2x4 wave grid, per-wave 128x64
  int l31 = lane & 31, hi = lane >> 5;
  int sw = (lane & 7) << 4;

  const char* xgb = (const char*)xb + (size_t)row0 * (KK * 2);
  const char* wgb = (const char*)wb + (size_t)col0 * (KK * 2);

  // staging addresses: LDS dest linear; source column pre-swizzled (rule #21).
  int o16 = t * 16;                 // 0..8176
  int srow = o16 >> 7;              // 0..63
  int spb = (o16 & 127) ^ ((srow & 7) << 4);
  const char* gaSrc = xgb + (size_t)srow * (KK * 2) + spb;
  const char* gbSrc = wgb + (size_t)srow * (KK * 2) + spb;

  auto stageA = [&](int buf, int h, int kt) {
    if (kt < NT) {
      const char* s = gaSrc + (size_t)h * (128 * KK * 2) + (size_t)kt * 128;
      char* d = lds + buf * 65536 + h * 16384 + o16;
      gload_lds16(s, d);
      gload_lds16(s + 64 * (KK * 2), d + 8192);
    }
  };
  auto stageB = [&](int buf, int h, int kt) {
    if (kt < NT) {
      const char* s = gbSrc + (size_t)h * (128 * KK * 2) + (size_t)kt * 128;
      char* d = lds + buf * 65536 + 32768 + h * 16384 + o16;
      gload_lds16(s, d);
      gload_lds16(s + 64 * (KK * 2), d + 8192);
    }
  };

  // ---- fragment read offsets ----
  // A row r = wm*128 + mf*32 + l31 (r&7 == lane&7); k-step ks reads bytes
  // [ks*32 + hi*16, +16) ^ ((r&7)<<4).  XOR computed per-ks (carry-unsafe).
  uint32_t aOffK[2][4], bOffK[2][4];
  #pragma unroll
  for (int buf = 0; buf < 2; ++buf)
    #pragma unroll
    for (int ks = 0; ks < 4; ++ks) {
      uint32_t ko = (uint32_t)((ks * 32 + hi * 16) ^ sw);
      aOffK[buf][ks] = buf * 65536u + (uint32_t)(wm * 128 + l31) * 128u + ko;
      bOffK[buf][ks] = buf * 65536u + 32768u + (uint32_t)(wn * 64 + l31) * 128u + ko;
    }

  short8 a[4], b2[2];
  floatx16 acc[4][2] = {};

#define KSTEP(buf, ks)                                                     \
  {                                                                        \
    _Pragma("unroll") for (int mf = 0; mf < 4; ++mf)                       \
        a[mf] = *(const short8*)(lds + aOffK[buf][ks] + mf * 4096);        \
    _Pragma("unroll") for (int nf = 0; nf < 2; ++nf)                       \
        b2[nf] = *(const short8*)(lds + bOffK[buf][ks] + nf * 4096);       \
    _Pragma("unroll") for (int mf = 0; mf < 4; ++mf)                       \
        _Pragma("unroll") for (int nf = 0; nf < 2; ++nf)                   \
            acc[mf][nf] = __builtin_amdgcn_mfma_f32_32x32x16_bf16(         \
                a[mf], b2[nf], acc[mf][nf], 0, 0, 0);                      \
  }

  // Prologue: stage tile 0 into buf 0, drain, sync.
  stageA(0, 0, 0); stageA(0, 1, 0);
  stageB(0, 0, 0); stageB(0, 1, 0);
  __syncthreads();

  #pragma unroll 1
  for (int kt = 0; kt < NT; ++kt) {
    int buf = kt & 1;
    stageA(buf ^ 1, 0, kt + 1); stageA(buf ^ 1, 1, kt + 1);
    stageB(buf ^ 1, 0, kt + 1); stageB(buf ^ 1, 1, kt + 1);
    __builtin_amdgcn_s_setprio(1);
    if (buf == 0) { KSTEP(0, 0); KSTEP(0, 1); KSTEP(0, 2); KSTEP(0, 3); }
    else          { KSTEP(1, 0); KSTEP(1, 1); KSTEP(1, 2); KSTEP(1, 3); }
    __builtin_amdgcn_s_setprio(0);
    __syncthreads();
  }

  // ---- fused epilogue: bias + GroupNorm(32) + SiLU * mw * SiLU ----
  // C/D: col = cb + nf*32 + l31; row = rb + mf*32 + (j&3) + 8*(j>>2) + 4*hi.
  // Each nf-frag spans exactly one group of 32 cols; group sum = 32-lane
  // reduce within the hi-half (4 DPP + 1 shfl_xor16).
  int cb = col0 + wn * 64;
  int rb = row0 + wm * 128;

  float bias_v[2], mw_v[2], gw_v[2], gb_v[2];
  #pragma unroll
  for (int nf = 0; nf < 2; ++nf) {
    int c = cb + nf * 32 + l31;
    bias_v[nf] = bias[c];
    mw_v[nf] = mw[c];
    int g = (cb >> 5) + nf;
    gw_v[nf] = gnw[g];
    gb_v[nf] = gnb[g];
  }

  #pragma unroll
  for (int mf = 0; mf < 4; ++mf) {
    #pragma unroll
    for (int nf = 0; nf < 2; ++nf) {
      int c = cb + nf * 32 + l31;
      #pragma unroll
      for (int j = 0; j < 16; ++j) {
        float v0 = acc[mf][nf][j] + bias_v[nf];
        float s = v0, ss = v0 * v0;
        RED32(s);
        RED32(ss);
        float mean = s * (1.0f / 32.0f);
        float var  = ss * (1.0f / 32.0f) - mean * mean;
        float rstd = rsqrtf(var + EPSV);
        float v = (v0 - mean) * rstd * gw_v[nf] + gb_v[nf];
        v = v / (1.0f + __expf(-v));   // SiLU
        v = v * mw_v[nf];
        v = v / (1.0f + __expf(-v));   // SiLU
        int r = rb + mf * 32 + (j & 3) + 8 * (j >> 2) + 4 * hi;
        out[(size_t)r * NN + c] = v;
      }
    }
  }
}

// ---------------- naive f32 fallback (only if ws too small) ----------------
__global__ void naive_gemm(const float* __restrict__ x, const float* __restrict__ w,
                           const float* __restrict__ bias, float* __restrict__ out) {
  size_t idx = (size_t)blockIdx.x * 256 + threadIdx.x;
  int m = (int)(idx >> 11);
  int n = (int)(idx & 2047);
  const float* xr = x + (size_t)m * KK;
  const float* wr = w + (size_t)n * KK;
  float s = bias[n];
  for (int k = 0; k < KK; k += 4)
    s += xr[k] * wr[k] + xr[k+1] * wr[k+1] + xr[k+2] * wr[k+2] + xr[k+3] * wr[k+3];
  out[idx] = s;
}

__global__ void naive_post(float* __restrict__ out, const float* __restrict__ gnw,
                           const float* __restrict__ gnb, const float* __restrict__ mw) {
  size_t idx = (size_t)blockIdx.x * 256 + threadIdx.x;  // M*G
  int m = (int)(idx >> 6);
  int g = (int)(idx & 63);
  float* p = out + (size_t)m * NN + g * 32;
  float s = 0.f, ss = 0.f;
  for (int j = 0; j < 32; ++j) { float v = p[j]; s += v; ss += v * v; }
  float mean = s * (1.0f / 32.0f);
  float var  = ss * (1.0f / 32.0f) - mean * mean;
  float rstd = rsqrtf(var + EPSV);
  float gw = gnw[g], gb = gnb[g];
  for (int j = 0; j < 32; ++j) {
    float v = (p[j] - mean) * rstd * gw + gb;
    v = v / (1.0f + __expf(-v));
    v = v * mw[g * 32 + j];
    v = v / (1.0f + __expf(-v));
    p[j] = v;
  }
}

extern "C" void kernel_launch(void* const* d_in, const int* in_sizes, int n_in,
                              void* d_out, int out_size, void* d_ws, size_t ws_size,
                              hipStream_t stream) {
  const float* x    = (const float*)d_in[0];
  const float* wgt  = (const float*)d_in[1];
  const float* bias = (const float*)d_in[2];
  const float* gnw  = (const float*)d_in[3];
  const float* gnb  = (const float*)d_in[4];
  const float* mwp  = (const float*)d_in[5];
  float* out = (float*)d_out;

  size_t need = ((size_t)MM * KK + (size_t)NN * KK) * 2;
  if (ws_size >= need) {
    uint16_t* xbf = (uint16_t*)d_ws;
    uint16_t* wbf = xbf + (size_t)MM * KK;
    cvt_f32_to_bf16<<<2048, 256, 0, stream>>>(x, xbf, (MM * KK) / 4);
    cvt_f32_to_bf16<<<512, 256, 0, stream>>>(wgt, wbf, (NN * KK) / 4);
    (void)hipFuncSetAttribute((const void*)gemm_gn_silu_32,
                              hipFuncAttributeMaxDynamicSharedMemorySize, 131072);
    gemm_gn_silu_32<<<512, 512, 131072, stream>>>(xbf, wbf, bias, gnw, gnb, mwp, out);
  } else {
    naive_gemm<<<(MM * (size_t)NN) / 256, 256, 0, stream>>>(x, wgt, bias, out);
    naive_post<<<(MM * GG) / 256, 256, 0, stream>>>(out, gnw, gnb, mwp);
  }
}

// Round 15
// 199.674 us; speedup vs baseline: 2.2874x; 2.2874x over previous
//
#include <hip/hip_runtime.h>
#include <stdint.h>

#define MM 16384
#define KK 2048
#define NN 2048
#define GG 64
#define EPSV 1e-5f
#define NT 32           // K tiles of 64

typedef short short8 __attribute__((ext_vector_type(8)));
typedef float floatx4 __attribute__((ext_vector_type(4)));

__device__ __forceinline__ uint16_t f2bf(float f) {
  uint32_t u = __float_as_uint(f);
  u = (u + 0x7fffu + ((u >> 16) & 1u)) >> 16;
  return (uint16_t)u;
}

__global__ void cvt_f32_to_bf16(const float* __restrict__ src,
                                uint16_t* __restrict__ dst, int n4) {
  int stride = gridDim.x * blockDim.x;
  for (int i = blockIdx.x * blockDim.x + threadIdx.x; i < n4; i += stride) {
    floatx4 v = __builtin_nontemporal_load(
        reinterpret_cast<const floatx4*>(src) + i);
    ushort4 o;
    o.x = f2bf(v.x); o.y = f2bf(v.y); o.z = f2bf(v.z); o.w = f2bf(v.w);
    reinterpret_cast<ushort4*>(dst)[i] = o;
  }
}

__device__ __forceinline__ void gload_lds16(const void* g, void* l) {
  __builtin_amdgcn_global_load_lds(
      (const __attribute__((address_space(1))) void*)g,
      (__attribute__((address_space(3))) void*)l, 16, 0, 0);
}

// DPP 16-lane row reduction (pure VALU, lanes [lhi*16..lhi*16+15] = DPP row).
#define ROR_ADD(v, n)                                                      \
  v += __int_as_float(__builtin_amdgcn_update_dpp(                         \
      0, __float_as_int(v), 0x120 + (n), 0xF, 0xF, true))
#define ROW_REDUCE(v) { ROR_ADD(v, 1); ROR_ADD(v, 2); ROR_ADD(v, 4); ROR_ADD(v, 8); }

// r15 = r11 (best: 206.1us total; GEMM 175us, MfmaUtil 34.5%, 0 conflicts)
// + nontemporal epilogue stores (write-once output; keep L2 for staging)
// + nontemporal cvt source loads (read-once f32 x; fixed: ext_vector type,
//   HIP_vector_type is rejected by __builtin_nontemporal_load).
// Search summary (r2-r13): 16x16x32 frags + 256x256 tile + 1-tile-ahead DMA
// staging + single barrier/K-tile is the local optimum; schedule levers
// (8-phase counted vmcnt, raw-asm barriers, read-ahead regs, wave parity),
// locality levers (XCD remaps), and demand levers (32x32 frags, B-in-reg,
// fused A-cvt) are all null or negative at source level on this shape.
__global__ __launch_bounds__(512, 2)
void gemm_gn_silu_ol(const uint16_t* __restrict__ xb,  // M x K bf16
                     const uint16_t* __restrict__ wb,  // N x K bf16
                     const float* __restrict__ bias,   // N
                     const float* __restrict__ gnw,    // G
                     const float* __restrict__ gnb,    // G
                     const float* __restrict__ mw,     // N
                     float* __restrict__ out) {        // M x N f32
  extern __shared__ char lds[];   // 131072 bytes

  int bid = blockIdx.x;
  // XCD chunk swizzle: 512 blocks, 8 XCDs, 64 consecutive tiles per XCD.
  int wgs = ((bid & 7) << 6) | (bid >> 3);
  int tm = wgs >> 3;          // 0..63  (M tiles)
  int tn = wgs & 7;           // 0..7   (N tiles)
  int row0 = tm * 256;
  int col0 = tn * 256;

  int t = threadIdx.x;
  int lane = t & 63;
  int wid = t >> 6;
  int wm = wid >> 2, wn = wid & 3;   // 2x4 wave grid
  int llo = lane & 15, lhi = lane >> 4;
  int sw = (llo & 7) << 4;

  const char* xgb = (const char*)xb + (size_t)row0 * (KK * 2);
  const char* wgb = (const char*)wb + (size_t)col0 * (KK * 2);

  // staging addresses: LDS dest linear; source column pre-swizzled (rule #21).
  int o16 = t * 16;                 // 0..8176
  int srow = o16 >> 7;              // 0..63
  int spb = (o16 & 127) ^ ((srow & 7) << 4);
  const char* gaSrc = xgb + (size_t)srow * (KK * 2) + spb;
  const char* gbSrc = wgb + (size_t)srow * (KK * 2) + spb;

  auto stageA = [&](int buf, int h, int kt) {
    if (kt < NT) {
      const char* s = gaSrc + (size_t)h * (128 * KK * 2) + (size_t)kt * 128;
      char* d = lds + buf * 65536 + h * 16384 + o16;
      gload_lds16(s, d);
      gload_lds16(s + 64 * (KK * 2), d + 8192);
    }
  };
  auto stageB = [&](int buf, int h, int kt) {
    if (kt < NT) {
      const char* s = gbSrc + (size_t)h * (128 * KK * 2) + (size_t)kt * 128;
      char* d = lds + buf * 65536 + 32768 + h * 16384 + o16;
      gload_lds16(s, d);
      gload_lds16(s + 64 * (KK * 2), d + 8192);
    }
  };

  // Precomputed LDS byte offsets: row = (wm*128+llo)+mh*64+mi2*16; (row&7)
  // == llo&7 for all frags -> swizzled k-offset fragment-invariant, fragment
  // selector is a compile-time immediate.
  uint32_t aOff[2][2], bOff[2][2];
  #pragma unroll
  for (int buf = 0; buf < 2; ++buf)
    #pragma unroll
    for (int kk = 0; kk < 2; ++kk) {
      uint32_t ko = (uint32_t)((kk * 64 + lhi * 16) ^ sw);
      aOff[buf][kk] = buf * 65536u + (uint32_t)(wm * 128 + llo) * 128u + ko;
      bOff[buf][kk] = buf * 65536u + 32768u + (uint32_t)(wn * 64 + llo) * 128u + ko;
    }

  short8 a[4][2], ah[4][2], blo[2][2], bhi[2][2];
  floatx4 acc[8][4] = {};

#define RDA(buf, mh, aa)                                                   \
  {                                                                        \
    _Pragma("unroll") for (int kk = 0; kk < 2; ++kk)                       \
        _Pragma("unroll") for (int mi2 = 0; mi2 < 4; ++mi2)                \
            aa[mi2][kk] = *(const short8*)(lds + aOff[buf][kk] +           \
                                           (mh)*8192 + mi2 * 2048);        \
  }
#define RDB(buf, nh, bq)                                                   \
  {                                                                        \
    _Pragma("unroll") for (int kk = 0; kk < 2; ++kk)                       \
        _Pragma("unroll") for (int ni2 = 0; ni2 < 2; ++ni2)                \
            bq[ni2][kk] = *(const short8*)(lds + bOff[buf][kk] +           \
                                           (nh)*4096 + ni2 * 2048);        \
  }
  // kk OUTER: 8 independent MFMAs between accumulator reuse.
#define MFMAQ(mh, nh, bq, aa)                                              \
  {                                                                        \
    _Pragma("unroll") for (int kk = 0; kk < 2; ++kk)                       \
        _Pragma("unroll") for (int mi2 = 0; mi2 < 4; ++mi2)                \
            _Pragma("unroll") for (int ni2 = 0; ni2 < 2; ++ni2)            \
                acc[(mh)*4 + mi2][(nh)*2 + ni2] =                          \
                    __builtin_amdgcn_mfma_f32_16x16x32_bf16(               \
                        aa[mi2][kk], bq[ni2][kk],                          \
                        acc[(mh)*4 + mi2][(nh)*2 + ni2], 0, 0, 0);         \
  }

  // Prologue: stage tile 0 into buf 0, drain, sync.
  stageA(0, 0, 0); stageA(0, 1, 0);
  stageB(0, 0, 0); stageB(0, 1, 0);
  __syncthreads();   // implicit vmcnt(0) drain: tile0 resident

  bool odd = (wid & 1) != 0;   // wave-uniform

  #pragma unroll 1
  for (int kt = 0; kt < NT; ++kt) {
    int buf = kt & 1;
    // stage next tile into the other buffer (8 gloads, 1 tile ahead)
    stageA(buf ^ 1, 0, kt + 1); stageA(buf ^ 1, 1, kt + 1);
    stageB(buf ^ 1, 0, kt + 1); stageB(buf ^ 1, 1, kt + 1);
    __builtin_amdgcn_s_setprio(1);
    if (!odd) {
      // even waves: quadrants (0,0),(0,1),(1,1),(1,0)
      if (buf == 0) { RDA(0, 0, a); RDB(0, 0, blo); RDB(0, 1, bhi); RDA(0, 1, ah); }
      else          { RDA(1, 0, a); RDB(1, 0, blo); RDB(1, 1, bhi); RDA(1, 1, ah); }
      MFMAQ(0, 0, blo, a);
      MFMAQ(0, 1, bhi, a);
      MFMAQ(1, 1, bhi, ah);
      MFMAQ(1, 0, blo, ah);
    } else {
      // odd waves: rotated by 2 -> (1,1),(1,0),(0,0),(0,1); read ah/bhi first
      if (buf == 0) { RDA(0, 1, ah); RDB(0, 1, bhi); RDB(0, 0, blo); RDA(0, 0, a); }
      else          { RDA(1, 1, ah); RDB(1, 1, bhi); RDB(1, 0, blo); RDA(1, 0, a); }
      MFMAQ(1, 1, bhi, ah);
      MFMAQ(1, 0, blo, ah);
      MFMAQ(0, 0, blo, a);
      MFMAQ(0, 1, bhi, a);
    }
    __builtin_amdgcn_s_setprio(0);
    __syncthreads();   // one barrier per K-tile; drains stage loads
  }

  // ---- fused epilogue: bias + GroupNorm(32) + SiLU * mw * SiLU ----
  // C/D frag: col = cb + ni*16 + llo ; row = rb + mi*16 + lhi*4 + j
  // Reduce groups = DPP rows (lanes lhi*16..lhi*16+15): pure-VALU row_ror.
  int cb = col0 + wn * 64;   // 2 groups of 32 per wave
  int rb = row0 + wm * 128;

  float bias_v[4], mw_v[4];
  #pragma unroll
  for (int ni = 0; ni < 4; ++ni) {
    int c = cb + ni * 16 + llo;
    bias_v[ni] = bias[c];
    mw_v[ni] = mw[c];
  }
  #pragma unroll
  for (int mi = 0; mi < 8; ++mi)
    #pragma unroll
    for (int ni = 0; ni < 4; ++ni)
      #pragma unroll
      for (int j = 0; j < 4; ++j)
        acc[mi][ni][j] += bias_v[ni];

  #pragma unroll
  for (int mi = 0; mi < 8; ++mi) {
    #pragma unroll
    for (int gp = 0; gp < 2; ++gp) {
      int g = (cb >> 5) + gp;
      float gw = gnw[g], gb = gnb[g];
      float s[4], ss[4];
      #pragma unroll
      for (int j = 0; j < 4; ++j) {
        float a0 = acc[mi][2 * gp][j];
        float a1 = acc[mi][2 * gp + 1][j];
        s[j] = a0 + a1;
        ss[j] = a0 * a0 + a1 * a1;
      }
      #pragma unroll
      for (int j = 0; j < 4; ++j) {
        ROW_REDUCE(s[j]);
        ROW_REDUCE(ss[j]);
      }
      #pragma unroll
      for (int j = 0; j < 4; ++j) {
        float mean = s[j] * (1.0f / 32.0f);
        float var  = ss[j] * (1.0f / 32.0f) - mean * mean;
        float rstd = rsqrtf(var + EPSV);
        int r = rb + mi * 16 + lhi * 4 + j;
        #pragma unroll
        for (int nn = 0; nn < 2; ++nn) {
          int ni = 2 * gp + nn;
          float v = (acc[mi][ni][j] - mean) * rstd * gw + gb;
          v = v / (1.0f + __expf(-v));   // SiLU
          v = v * mw_v[ni];
          v = v / (1.0f + __expf(-v));   // SiLU
          __builtin_nontemporal_store(
              v, out + (size_t)r * NN + (cb + ni * 16 + llo));
        }
      }
    }
  }
}

// ---------------- naive f32 fallback (only if ws too small) ----------------
__global__ void naive_gemm(const float* __restrict__ x, const float* __restrict__ w,
                           const float* __restrict__ bias, float* __restrict__ out) {
  size_t idx = (size_t)blockIdx.x * 256 + threadIdx.x;
  int m = (int)(idx >> 11);
  int n = (int)(idx & 2047);
  const float* xr = x + (size_t)m * KK;
  const float* wr = w + (size_t)n * KK;
  float s = bias[n];
  for (int k = 0; k < KK; k += 4)
    s += xr[k] * wr[k] + xr[k+1] * wr[k+1] + xr[k+2] * wr[k+2] + xr[k+3] * wr[k+3];
  out[idx] = s;
}

__global__ void naive_post(float* __restrict__ out, const float* __restrict__ gnw,
                           const float* __restrict__ gnb, const float* __restrict__ mw) {
  size_t idx = (size_t)blockIdx.x * 256 + threadIdx.x;  // M*G
  int m = (int)(idx >> 6);
  int g = (int)(idx & 63);
  float* p = out + (size_t)m * NN + g * 32;
  float s = 0.f, ss = 0.f;
  for (int j = 0; j < 32; ++j) { float v = p[j]; s += v; ss += v * v; }
  float mean = s * (1.0f / 32.0f);
  float var  = ss * (1.0f / 32.0f) - mean * mean;
  float rstd = rsqrtf(var + EPSV);
  float gw = gnw[g], gb = gnb[g];
  for (int j = 0; j < 32; ++j) {
    float v = (p[j] - mean) * rstd * gw + gb;
    v = v / (1.0f + __expf(-v));
    v = v * mw[g * 32 + j];
    v = v / (1.0f + __expf(-v));
    p[j] = v;
  }
}

extern "C" void kernel_launch(void* const* d_in, const int* in_sizes, int n_in,
                              void* d_out, int out_size, void* d_ws, size_t ws_size,
                              hipStream_t stream) {
  const float* x    = (const float*)d_in[0];
  const float* wgt  = (const float*)d_in[1];
  const float* bias = (const float*)d_in[2];
  const float* gnw  = (const float*)d_in[3];
  const float* gnb  = (const float*)d_in[4];
  const float* mwp  = (const float*)d_in[5];
  float* out = (float*)d_out;

  size_t need = ((size_t)MM * KK + (size_t)NN * KK) * 2;
  if (ws_size >= need) {
    uint16_t* xbf = (uint16_t*)d_ws;
    uint16_t* wbf = xbf + (size_t)MM * KK;
    cvt_f32_to_bf16<<<2048, 256, 0, stream>>>(x, xbf, (MM * KK) / 4);
    cvt_f32_to_bf16<<<512, 256, 0, stream>>>(wgt, wbf, (NN * KK) / 4);
    (void)hipFuncSetAttribute((const void*)gemm_gn_silu_ol,
                              hipFuncAttributeMaxDynamicSharedMemorySize, 131072);
    gemm_gn_silu_ol<<<512, 512, 131072, stream>>>(xbf, wbf, bias, gnw, gnb, mwp, out);
  } else {
    naive_gemm<<<(MM * (size_t)NN) / 256, 256, 0, stream>>>(x, wgt, bias, out);
    naive_post<<<(MM * GG) / 256, 256, 0, stream>>>(out, gnw, gnb, mwp);
  }
}